// Round 1
// baseline (688.539 us; speedup 1.0000x reference)
//
#include <hip/hip_runtime.h>

// VanillaLinearAttention pipeline, bf16-MFMA GEMMs + fp32 softmax/attention core.
// B=8 N=4096 C=1024 H=16 D=64. M = B*N = 32768.
//
// ws layout (286.6 MB):
//   xb   : bf16[32768*1024]        x cast to bf16
//   wt   : bf16[3072*1024]         [Wq^T;Wk^T;Wv^T]  (row n, col k)
//   wot  : bf16[1024*1024]         Wo^T
//   qkv  : bf16[32768*3072]        Q|K|V row-major; Q later overwritten by y
//   psum : f32[8*8192]             k-softmax partial exp-sums
//   cinv : f32[8192]               1/colsum
//   kvp  : f32[4*128*4096]         kv partials (4 n-chunks)
//   kvTb : bf16[128*4096]          kv^T per (b,h): [d][f]

typedef unsigned short u16;
typedef __bf16 bf16x8v __attribute__((ext_vector_type(8)));
typedef float f32x4 __attribute__((ext_vector_type(4)));
typedef u16 u16x8 __attribute__((ext_vector_type(8)));
typedef u16 u16x4 __attribute__((ext_vector_type(4)));

#define AS1C(p) (const __attribute__((address_space(1))) void*)(p)
#define AS3(p)  (__attribute__((address_space(3))) void*)(p)

__device__ __forceinline__ float b2f(u16 u) {
    union { unsigned u; float f; } c; c.u = ((unsigned)u) << 16; return c.f;
}
__device__ __forceinline__ u16 f2b(float f) {
    union { float f; unsigned u; } c; c.f = f;
    unsigned x = c.u + 0x7fffu + ((c.u >> 16) & 1u);   // RNE
    return (u16)(x >> 16);
}

// ---------------- cast x fp32 -> bf16 (float4 vectorized) ----------------
__global__ void cast_x_kernel(const float* __restrict__ in, u16* __restrict__ out, long n4) {
    long i = (long)blockIdx.x * blockDim.x + threadIdx.x;
    long stride = (long)gridDim.x * blockDim.x;
    for (long j = i; j < n4; j += stride) {
        float4 v = ((const float4*)in)[j];
        u16x4 o = { f2b(v.x), f2b(v.y), f2b(v.z), f2b(v.w) };
        ((u16x4*)out)[j] = o;
    }
}

// ------------- transpose+cast 1024x1024: dst[n][k] = src[k][n] -------------
__global__ void transpose_cast(const float* __restrict__ src, u16* __restrict__ dst) {
    __shared__ float tl[64][65];
    int tx = blockIdx.x & 15, ty = blockIdx.x >> 4;
    int j = threadIdx.x & 63, i0 = threadIdx.x >> 6;
    #pragma unroll
    for (int it = 0; it < 16; ++it) {
        int i = it * 4 + i0;
        tl[i][j] = src[(ty * 64 + i) * 1024 + tx * 64 + j];
    }
    __syncthreads();
    #pragma unroll
    for (int it = 0; it < 16; ++it) {
        int i = it * 4 + i0;
        dst[(tx * 64 + i) * 1024 + ty * 64 + j] = f2b(tl[j][i]);
    }
}

// ---------------- 128x128-tile bf16 NT-GEMM (m97 structure) ----------------
// C[M][N] = A[M][K] * Bt[N][K]^T.  BK=32, 4 waves (2x2), 4x4 16x16x32 frags/wave.
// OUTMODE 0: bf16 out; 1: f32 out + bias.
template<int OUTMODE>
__global__ __launch_bounds__(256) void gemm_bt(
    const u16* __restrict__ A, const u16* __restrict__ Bt,
    void* __restrict__ Cout, const float* __restrict__ bias,
    const int K, const int lda, const int ldc, const int ntn)
{
    __shared__ __align__(16) u16 As[4096];   // [128 rows][32 k]
    __shared__ __align__(16) u16 Bs[4096];   // [128 n-rows][32 k]
    const int tid = threadIdx.x;
    const int bx = blockIdx.x;
    const int tm = bx / ntn, tn = bx - tm * ntn;
    const long row0 = (long)tm << 7, col0 = (long)tn << 7;
    const int wave = tid >> 6, lane = tid & 63;
    const int wr = wave >> 1, wc = wave & 1;
    const int l16 = lane & 15, g = lane >> 4;

    // staging: chunk c covers rows c*64 + tid/4, k-col (tid&3)*8; 16B/lane
    const int srow = tid >> 2, skc = (tid & 3) << 3;
    const u16* aP = A + (row0 + srow) * (long)lda + skc;
    const u16* bP = Bt + (col0 + srow) * (long)K + skc;
    const long aStep = (long)lda << 6;   // 64 rows
    const long bStep = (long)K << 6;

    u16* lA = As + wave * 512;           // wave-uniform LDS base (bytes: wave*1024)
    u16* lB = Bs + wave * 512;

    f32x4 acc[4][4] = {};

    for (int k0 = 0; k0 < K; k0 += 32) {
        __builtin_amdgcn_global_load_lds(AS1C(aP + k0),         AS3(lA),        16, 0, 0);
        __builtin_amdgcn_global_load_lds(AS1C(aP + k0 + aStep), AS3(lA + 2048), 16, 0, 0);
        __builtin_amdgcn_global_load_lds(AS1C(bP + k0),         AS3(lB),        16, 0, 0);
        __builtin_amdgcn_global_load_lds(AS1C(bP + k0 + bStep), AS3(lB + 2048), 16, 0, 0);
        __syncthreads();
        bf16x8v af[4], bfv[4];
        #pragma unroll
        for (int mi = 0; mi < 4; ++mi)
            af[mi] = __builtin_bit_cast(bf16x8v,
                *(const u16x8*)&As[(wr * 64 + mi * 16 + l16) * 32 + g * 8]);
        #pragma unroll
        for (int ni = 0; ni < 4; ++ni)
            bfv[ni] = __builtin_bit_cast(bf16x8v,
                *(const u16x8*)&Bs[(wc * 64 + ni * 16 + l16) * 32 + g * 8]);
        #pragma unroll
        for (int mi = 0; mi < 4; ++mi) {
            #pragma unroll
            for (int ni = 0; ni < 4; ++ni)
                acc[mi][ni] = __builtin_amdgcn_mfma_f32_16x16x32_bf16(
                    af[mi], bfv[ni], acc[mi][ni], 0, 0, 0);
        }
        __syncthreads();
    }

    // C/D layout: col = lane&15, row = (lane>>4)*4 + reg
    const long crow = row0 + wr * 64 + g * 4;
    const long ccol = col0 + wc * 64 + l16;
    if (OUTMODE == 0) {
        u16* Cb = (u16*)Cout;
        #pragma unroll
        for (int mi = 0; mi < 4; ++mi) {
            #pragma unroll
            for (int ni = 0; ni < 4; ++ni) {
                long base = (crow + mi * 16) * (long)ldc + ccol + ni * 16;
                #pragma unroll
                for (int r = 0; r < 4; ++r)
                    Cb[base + (long)r * ldc] = f2b(acc[mi][ni][r]);
            }
        }
    } else {
        float* Cf = (float*)Cout;
        float bv[4];
        #pragma unroll
        for (int ni = 0; ni < 4; ++ni) bv[ni] = bias[ccol + ni * 16];
        #pragma unroll
        for (int mi = 0; mi < 4; ++mi) {
            #pragma unroll
            for (int ni = 0; ni < 4; ++ni) {
                long base = (crow + mi * 16) * (long)ldc + ccol + ni * 16;
                #pragma unroll
                for (int r = 0; r < 4; ++r)
                    Cf[base + (long)r * ldc] = acc[mi][ni][r] + bv[ni];
            }
        }
    }
}

// --------- q softmax over head_dim (64 contiguous), one wave per head-row ---------
__global__ void softmax_q(u16* __restrict__ qkv) {
    const int wave = threadIdx.x >> 6, lane = threadIdx.x & 63;
    const long hr = (long)blockIdx.x * 4 + wave;     // 0..524287
    const long row = hr >> 4; const int h = (int)(hr & 15);
    u16* p = qkv + row * 3072 + h * 64 + lane;
    float v = b2f(*p);
    float m = v;
    #pragma unroll
    for (int off = 32; off > 0; off >>= 1) m = fmaxf(m, __shfl_xor(m, off));
    float e = expf(v - m);
    float s = e;
    #pragma unroll
    for (int off = 32; off > 0; off >>= 1) s += __shfl_xor(s, off);
    *p = f2b(e / s * 0.125f);    // * D^-0.5
}

// --------- k softmax over sequence: column partial exp-sums (no max needed) ---------
__global__ void k_colsum(const u16* __restrict__ qkv, float* __restrict__ psum) {
    const int bx = blockIdx.x;                       // 256 = 8nc * 4cc * 8b
    const int nc = bx & 7, cc = (bx >> 3) & 3, b = bx >> 5;
    const int c = cc * 256 + threadIdx.x;
    const u16* p = qkv + ((long)b * 4096 + nc * 512) * 3072 + 1024 + c;
    float s = 0.f;
    for (int n = 0; n < 512; ++n) { s += expf(b2f(*p)); p += 3072; }
    psum[nc * 8192 + b * 1024 + c] = s;
}
__global__ void k_colinv(const float* __restrict__ psum, float* __restrict__ cinv) {
    const int i = blockIdx.x * 256 + threadIdx.x;    // 0..8191
    float s = 0.f;
    #pragma unroll
    for (int nc = 0; nc < 8; ++nc) s += psum[nc * 8192 + i];
    cinv[i] = 1.0f / s;
}
__global__ void k_norm(u16* __restrict__ qkv, const float* __restrict__ cinv) {
    const int bx = blockIdx.x;
    const int nc = bx & 7, cc = (bx >> 3) & 3, b = bx >> 5;
    const int c = cc * 256 + threadIdx.x;
    u16* p = qkv + ((long)b * 4096 + nc * 512) * 3072 + 1024 + c;
    const float inv = cinv[b * 1024 + c];
    for (int n = 0; n < 512; ++n) { *p = f2b(expf(b2f(*p)) * inv); p += 3072; }
}

// --------- kv[b,h,f,d] = sum_n kf[b,n,h,f] * v[b,n,h,d]  (VALU, n split 4-way) ---------
__global__ __launch_bounds__(256) void kv_partial(const u16* __restrict__ qkv,
                                                  float* __restrict__ kvp) {
    __shared__ __align__(16) u16 kf_s[64 * 64];
    __shared__ __align__(16) u16 v_s[64 * 64];
    const int t = threadIdx.x;
    const int bx = blockIdx.x;                       // 512 = 4nc * 16h * 8b
    const int nc = bx & 3, h = (bx >> 2) & 15, b = bx >> 6;
    const int f0 = (t >> 4) << 2;                    // 0..60
    const int d0 = (t & 15) << 2;
    const int lr = t >> 3, lc = (t & 7) << 3;
    const long rowbase = (long)b * 4096 + nc * 1024;
    const u16* kfg = qkv + (rowbase + lr) * 3072 + 1024 + h * 64 + lc;
    const u16* vg = kfg + 1024;
    float acc[4][4] = {};
    for (int n0 = 0; n0 < 1024; n0 += 64) {
        long go = (long)n0 * 3072;
        *(u16x8*)&kf_s[lr * 64 + lc]        = *(const u16x8*)(kfg + go);
        *(u16x8*)&kf_s[(lr + 32) * 64 + lc] = *(const u16x8*)(kfg + go + 32L * 3072);
        *(u16x8*)&v_s[lr * 64 + lc]         = *(const u16x8*)(vg + go);
        *(u16x8*)&v_s[(lr + 32) * 64 + lc]  = *(const u16x8*)(vg + go + 32L * 3072);
        __syncthreads();
        #pragma unroll 8
        for (int r = 0; r < 64; ++r) {
            u16x4 ku = *(const u16x4*)&kf_s[r * 64 + f0];
            u16x4 vu = *(const u16x4*)&v_s[r * 64 + d0];
            float kf4[4], vf4[4];
            #pragma unroll
            for (int i = 0; i < 4; ++i) { kf4[i] = b2f(ku[i]); vf4[i] = b2f(vu[i]); }
            #pragma unroll
            for (int i = 0; i < 4; ++i) {
                #pragma unroll
                for (int jj = 0; jj < 4; ++jj)
                    acc[i][jj] += kf4[i] * vf4[jj];
            }
        }
        __syncthreads();
    }
    float* o = kvp + (long)nc * 524288 + ((long)(b * 16 + h)) * 4096;
    #pragma unroll
    for (int i = 0; i < 4; ++i) {
        #pragma unroll
        for (int jj = 0; jj < 4; ++jj)
            o[(f0 + i) * 64 + d0 + jj] = acc[i][jj];
    }
}

// --------- combine 4 kv partials + transpose -> kvTb[b,h][d][f] bf16 ---------
__global__ void kv_combine_T(const float* __restrict__ kvp, u16* __restrict__ kvTb) {
    __shared__ float tl[64 * 65];
    const int bh = blockIdx.x;                       // 128
    const float* p = kvp + (long)bh * 4096;
    const int t = threadIdx.x;
    #pragma unroll
    for (int it = 0; it < 16; ++it) {
        int idx = it * 256 + t;                      // idx = f*64 + d
        float v = p[idx] + p[524288 + idx] + p[1048576 + idx] + p[1572864 + idx];
        tl[(idx & 63) * 65 + (idx >> 6)] = v;        // tl[d][f]
    }
    __syncthreads();
    u16* o = kvTb + (long)bh * 4096;
    #pragma unroll
    for (int it = 0; it < 16; ++it) {
        int idx = it * 256 + t;                      // idx = d*64 + f
        o[idx] = f2b(tl[(idx >> 6) * 65 + (idx & 63)]);
    }
}

// --------- y = qf @ kv per (b,h): MFMA, 128 rows x 64 cols, K=64; in-place over Q ---------
__global__ __launch_bounds__(256) void apply_mfma(u16* __restrict__ qkv,
                                                  const u16* __restrict__ kvTb) {
    __shared__ __align__(16) u16 Qs[8192];   // [128][64]
    __shared__ __align__(16) u16 Bs2[4096];  // [64 d][64 f]
    const int tid = threadIdx.x;
    const int bx = blockIdx.x;               // 4096 = 32nt * 16h * 8b
    const int nt = bx & 31, h = (bx >> 5) & 15, b = bx >> 9;
    const long n0 = (long)b * 4096 + (long)nt * 128;
    const int wave = tid >> 6, lane = tid & 63;
    const int wr = wave >> 1, wc = wave & 1;
    const int l16 = lane & 15, g = lane >> 4;

    const u16* qsrc = qkv + (n0 + (tid >> 3)) * 3072 + h * 64 + ((tid & 7) << 3);
    u16* lq = Qs + wave * 512;
    #pragma unroll
    for (int c = 0; c < 4; ++c)
        __builtin_amdgcn_global_load_lds(AS1C(qsrc + (long)c * (32L * 3072)),
                                         AS3(lq + c * 2048), 16, 0, 0);
    const u16* bsrc = kvTb + ((long)(b * 16 + h) << 12) + (tid << 3);
    u16* lb = Bs2 + wave * 512;
    #pragma unroll
    for (int c = 0; c < 2; ++c)
        __builtin_amdgcn_global_load_lds(AS1C(bsrc + c * 2048),
                                         AS3(lb + c * 2048), 16, 0, 0);
    __syncthreads();

    bf16x8v aq[4][2], bkv[2][2];
    #pragma unroll
    for (int mi = 0; mi < 4; ++mi) {
        #pragma unroll
        for (int ks = 0; ks < 2; ++ks)
            aq[mi][ks] = __builtin_bit_cast(bf16x8v,
                *(const u16x8*)&Qs[(wr * 64 + mi * 16 + l16) * 64 + ks * 32 + g * 8]);
    }
    #pragma unroll
    for (int ni = 0; ni < 2; ++ni) {
        #pragma unroll
        for (int ks = 0; ks < 2; ++ks)
            bkv[ni][ks] = __builtin_bit_cast(bf16x8v,
                *(const u16x8*)&Bs2[(wc * 32 + ni * 16 + l16) * 64 + ks * 32 + g * 8]);
    }
    f32x4 acc[4][2] = {};
    #pragma unroll
    for (int mi = 0; mi < 4; ++mi) {
        #pragma unroll
        for (int ni = 0; ni < 2; ++ni) {
            acc[mi][ni] = __builtin_amdgcn_mfma_f32_16x16x32_bf16(
                aq[mi][0], bkv[ni][0], acc[mi][ni], 0, 0, 0);
            acc[mi][ni] = __builtin_amdgcn_mfma_f32_16x16x32_bf16(
                aq[mi][1], bkv[ni][1], acc[mi][ni], 0, 0, 0);
        }
    }
    #pragma unroll
    for (int mi = 0; mi < 4; ++mi) {
        #pragma unroll
        for (int ni = 0; ni < 2; ++ni) {
            long row = n0 + wr * 64 + mi * 16 + g * 4;
            int col = h * 64 + wc * 32 + ni * 16 + l16;
            #pragma unroll
            for (int r = 0; r < 4; ++r)
                qkv[(row + r) * 3072 + col] = f2b(acc[mi][ni][r]);
        }
    }
}

extern "C" void kernel_launch(void* const* d_in, const int* in_sizes, int n_in,
                              void* d_out, int out_size, void* d_ws, size_t ws_size,
                              hipStream_t stream) {
    (void)in_sizes; (void)n_in; (void)out_size; (void)ws_size;
    const float* x  = (const float*)d_in[0];
    const float* Wq = (const float*)d_in[1];
    const float* Wk = (const float*)d_in[2];
    const float* Wv = (const float*)d_in[3];
    const float* Wo = (const float*)d_in[4];
    const float* bo = (const float*)d_in[5];

    u16* xb  = (u16*)d_ws;                       // 33,554,432 elems
    u16* wt  = xb + 33554432;                    //  3,145,728
    u16* wot = wt + 3145728;                     //  1,048,576
    u16* qkv = wot + 1048576;                    // 100,663,296
    float* psum = (float*)(qkv + 100663296);     //     65,536
    float* cinv = psum + 65536;                  //      8,192
    float* kvp  = cinv + 8192;                   //  2,097,152
    u16*   kvTb = (u16*)(kvp + 2097152);         //    524,288

    cast_x_kernel<<<2048, 256, 0, stream>>>(x, xb, 8388608L);
    transpose_cast<<<256, 256, 0, stream>>>(Wq, wt);
    transpose_cast<<<256, 256, 0, stream>>>(Wk, wt + 1048576);
    transpose_cast<<<256, 256, 0, stream>>>(Wv, wt + 2097152);
    transpose_cast<<<256, 256, 0, stream>>>(Wo, wot);
    // QKV = xb @ [Wq|Wk|Wv]   (M=32768, N=3072, K=1024)
    gemm_bt<0><<<6144, 256, 0, stream>>>(xb, wt, (void*)qkv, nullptr, 1024, 1024, 3072, 24);
    softmax_q<<<131072, 256, 0, stream>>>(qkv);
    k_colsum<<<256, 256, 0, stream>>>(qkv, psum);
    k_colinv<<<32, 256, 0, stream>>>(psum, cinv);
    k_norm<<<256, 256, 0, stream>>>(qkv, cinv);
    kv_partial<<<512, 256, 0, stream>>>(qkv, kvp);
    kv_combine_T<<<128, 256, 0, stream>>>(kvp, kvTb);
    apply_mfma<<<4096, 256, 0, stream>>>(qkv, kvTb);
    // out = y @ Wo + bo   (M=32768, N=1024, K=1024), y lives in Q region (lda=3072)
    gemm_bt<1><<<2048, 256, 0, stream>>>(qkv, wot, d_out, bo, 1024, 3072, 1024, 8);
}

// Round 2
// 476.115 us; speedup vs baseline: 1.4462x; 1.4462x over previous
//
#include <hip/hip_runtime.h>

// VanillaLinearAttention: B=8 N=4096 C=1024 H=16 D=64, M=B*N=32768.
// Pipeline: cast x -> bf16; transpose W's; QKV = x@[Wq|Wk|Wv] (256^2-tile
// counted-vmcnt MFMA GEMM); kv = sum_n exp(k)*v with colsum side-product
// (exp fused in staging); kv_combine applies 1/colsum + transpose;
// apply = softmax_q fused + q@kvT MFMA (y in-place over Q); out = y@Wo + bo.

typedef unsigned short u16;
typedef __bf16 bf16x8v __attribute__((ext_vector_type(8)));
typedef float f32x4 __attribute__((ext_vector_type(4)));
typedef u16 u16x8 __attribute__((ext_vector_type(8)));
typedef u16 u16x4 __attribute__((ext_vector_type(4)));

#define AS1C(p) (const __attribute__((address_space(1))) void*)(p)
#define AS3(p)  (__attribute__((address_space(3))) void*)(p)

__device__ __forceinline__ float b2f(u16 u) {
    union { unsigned u; float f; } c; c.u = ((unsigned)u) << 16; return c.f;
}
__device__ __forceinline__ u16 f2b(float f) {
    union { float f; unsigned u; } c; c.f = f;
    unsigned x = c.u + 0x7fffu + ((c.u >> 16) & 1u);   // RNE
    return (u16)(x >> 16);
}

// ---------------- cast x fp32 -> bf16 ----------------
__global__ void cast_x_kernel(const float* __restrict__ in, u16* __restrict__ out, long n4) {
    long i = (long)blockIdx.x * blockDim.x + threadIdx.x;
    long stride = (long)gridDim.x * blockDim.x;
    for (long j = i; j < n4; j += stride) {
        float4 v = ((const float4*)in)[j];
        u16x4 o = { f2b(v.x), f2b(v.y), f2b(v.z), f2b(v.w) };
        ((u16x4*)out)[j] = o;
    }
}

// ------------- transpose+cast 1024x1024: dst[n][k] = src[k][n] -------------
__global__ void transpose_cast(const float* __restrict__ src, u16* __restrict__ dst) {
    __shared__ float tl[64][65];
    int tx = blockIdx.x & 15, ty = blockIdx.x >> 4;
    int j = threadIdx.x & 63, i0 = threadIdx.x >> 6;
    #pragma unroll
    for (int it = 0; it < 16; ++it) {
        int i = it * 4 + i0;
        tl[i][j] = src[(ty * 64 + i) * 1024 + tx * 64 + j];
    }
    __syncthreads();
    #pragma unroll
    for (int it = 0; it < 16; ++it) {
        int i = it * 4 + i0;
        dst[(tx * 64 + i) * 1024 + ty * 64 + j] = f2b(tl[j][i]);
    }
}

// ================= 256x256-tile NT-GEMM, BK=32, counted-vmcnt 4-buf ring ======
// C[M][N] = A[M][K=1024] * Bt[N][1024]^T.  512 thr = 8 waves (2M x 4N),
// per-wave 128x64 = 8x4 16x16x32 frags. LDS: 4 bufs x (A 16K + B 16K) = 128 KB.
// Stage: pre-swizzled global source + linear global_load_lds dest; frag reads
// XOR-swizzled (chunk ^= row&3). vmcnt(10) per tile (3 tiles + A-half in flight).
template<int OUTMODE>
__global__ __launch_bounds__(512, 2) void gemm256(
    const u16* __restrict__ A, const u16* __restrict__ Bt,
    void* __restrict__ Cout, const float* __restrict__ bias,
    const int lda, const int ldc, const int ntn, const int nwg)
{
    __shared__ __align__(16) u16 lds[65536];   // 128 KB
    const int t = threadIdx.x;
    const int w = t >> 6, lane = t & 63;
    const int l16 = lane & 15, g = lane >> 4;
    const int wr = w >> 2, wc = w & 3;

    // XCD-aware bijective swizzle (nwg % 8 == 0)
    const int cpx = nwg >> 3;
    const int bid = blockIdx.x;
    const int swzb = (bid & 7) * cpx + (bid >> 3);
    const int tm = swzb / ntn, tn = swzb - tm * ntn;
    const long row0 = (long)tm << 8, col0 = (long)tn << 8;

    // staging addressing: chunk c (16B): row=c>>2, slot=c&3 holds k-chunk (c&3)^(row&3)
    const int r0 = t >> 2;
    const int eo = (((t & 3) ^ ((t >> 2) & 3)) << 3);     // element offset within 32-k row
    const u16* pa0 = A + (row0 + r0) * (long)lda + eo;
    const u16* pa1 = A + (row0 + 128 + r0) * (long)lda + eo;
    const u16* pb0 = Bt + (col0 + r0) * 1024L + eo;
    const u16* pb1 = Bt + (col0 + 128 + r0) * 1024L + eo;
    const int wB = w << 9;                                 // wave LDS base (elems)

#define STAGE_A(Tt) { const int _b = ((Tt)&3)*16384; const int _k = ((Tt)&31)*32;        \
    __builtin_amdgcn_global_load_lds(AS1C(pa0 + _k), AS3(lds + _b + wB), 16, 0, 0);      \
    __builtin_amdgcn_global_load_lds(AS1C(pa1 + _k), AS3(lds + _b + 4096 + wB), 16, 0, 0); }
#define STAGE_B(Tt) { const int _b = ((Tt)&3)*16384; const int _k = ((Tt)&31)*32;        \
    __builtin_amdgcn_global_load_lds(AS1C(pb0 + _k), AS3(lds + _b + 8192 + wB), 16, 0, 0);  \
    __builtin_amdgcn_global_load_lds(AS1C(pb1 + _k), AS3(lds + _b + 12288 + wB), 16, 0, 0); }

    // prologue: prefetch tiles 0,1,2 (12 loads/wave in flight)
    STAGE_A(0); STAGE_B(0);
    STAGE_A(1); STAGE_B(1);
    STAGE_A(2); STAGE_B(2);

    f32x4 acc[8][4] = {};
    const int sw = (g ^ (l16 & 3)) << 3;       // frag-read swizzle (row&3 == l16&3)
    const int arow = wr * 128 + l16;           // A frag base row
    const int brow = wc * 64 + l16;            // B frag base row

    #pragma unroll 4
    for (int T = 0; T < 32; ++T) {
        const int bufE = (T & 3) * 16384;
        const int Tn = T + 3;
        // ---- phase 0: issue A-stage(T+3); wait tile T; quadrant mi 0..3 ----
        STAGE_A(Tn);
        asm volatile("s_waitcnt vmcnt(10)" ::: "memory");
        __builtin_amdgcn_s_barrier();
        __builtin_amdgcn_sched_barrier(0);
        bf16x8v bfr[4], afr[4];
        #pragma unroll
        for (int ni = 0; ni < 4; ++ni)
            bfr[ni] = __builtin_bit_cast(bf16x8v,
                *(const u16x8*)&lds[bufE + 8192 + (brow + ni * 16) * 32 + sw]);
        #pragma unroll
        for (int mi = 0; mi < 4; ++mi)
            afr[mi] = __builtin_bit_cast(bf16x8v,
                *(const u16x8*)&lds[bufE + (arow + mi * 16) * 32 + sw]);
        __builtin_amdgcn_s_setprio(1);
        #pragma unroll
        for (int mi = 0; mi < 4; ++mi) {
            #pragma unroll
            for (int ni = 0; ni < 4; ++ni)
                acc[mi][ni] = __builtin_amdgcn_mfma_f32_16x16x32_bf16(
                    afr[mi], bfr[ni], acc[mi][ni], 0, 0, 0);
        }
        __builtin_amdgcn_s_setprio(0);
        // ---- phase 1: issue B-stage(T+3); quadrant mi 4..7 ----
        STAGE_B(Tn);
        bf16x8v afr2[4];
        #pragma unroll
        for (int mi = 0; mi < 4; ++mi)
            afr2[mi] = __builtin_bit_cast(bf16x8v,
                *(const u16x8*)&lds[bufE + (arow + 64 + mi * 16) * 32 + sw]);
        __builtin_amdgcn_s_setprio(1);
        #pragma unroll
        for (int mi = 0; mi < 4; ++mi) {
            #pragma unroll
            for (int ni = 0; ni < 4; ++ni)
                acc[4 + mi][ni] = __builtin_amdgcn_mfma_f32_16x16x32_bf16(
                    afr2[mi], bfr[ni], acc[4 + mi][ni], 0, 0, 0);
        }
        __builtin_amdgcn_s_setprio(0);
        __builtin_amdgcn_s_barrier();          // all waves done reading buf[T&3]
        __builtin_amdgcn_sched_barrier(0);
    }
    asm volatile("s_waitcnt vmcnt(0)" ::: "memory");   // drain tail stages
#undef STAGE_A
#undef STAGE_B

    // C/D: col = lane&15, row = (lane>>4)*4 + reg
    const long crow = row0 + wr * 128 + g * 4;
    const long ccol = col0 + wc * 64 + l16;
    if (OUTMODE == 0) {
        u16* Cb = (u16*)Cout;
        #pragma unroll
        for (int mi = 0; mi < 8; ++mi) {
            #pragma unroll
            for (int ni = 0; ni < 4; ++ni) {
                long base = (crow + mi * 16) * (long)ldc + ccol + ni * 16;
                #pragma unroll
                for (int r = 0; r < 4; ++r)
                    Cb[base + (long)r * ldc] = f2b(acc[mi][ni][r]);
            }
        }
    } else {
        float* Cf = (float*)Cout;
        float bv[4];
        #pragma unroll
        for (int ni = 0; ni < 4; ++ni) bv[ni] = bias[ccol + ni * 16];
        #pragma unroll
        for (int mi = 0; mi < 8; ++mi) {
            #pragma unroll
            for (int ni = 0; ni < 4; ++ni) {
                long base = (crow + mi * 16) * (long)ldc + ccol + ni * 16;
                #pragma unroll
                for (int r = 0; r < 4; ++r)
                    Cf[base + (long)r * ldc] = acc[mi][ni][r] + bv[ni];
            }
        }
    }
}

// --------- kv[b,h,f,d] = sum_n exp(k_raw)[n,h,f] * v[n,h,d]; colsum side-product ---
__global__ __launch_bounds__(256) void kv_partial(const u16* __restrict__ qkv,
                                                  float* __restrict__ kvp,
                                                  float* __restrict__ psum) {
    __shared__ __align__(16) u16 kf_s[64 * 64];
    __shared__ __align__(16) u16 v_s[64 * 64];
    const int t = threadIdx.x;
    const int bx = blockIdx.x;                       // 512 = 4nc * 16h * 8b
    const int nc = bx & 3, h = (bx >> 2) & 15, b = bx >> 6;
    const int f0 = (t >> 4) << 2;                    // 0..60
    const int d0 = (t & 15) << 2;
    const int lr = t >> 3, lc = (t & 7) << 3;
    const long rowbase = (long)b * 4096 + nc * 1024;
    const u16* kfg = qkv + (rowbase + lr) * 3072 + 1024 + h * 64 + lc;
    const u16* vg = kfg + 1024;
    float acc[4][4] = {};
    float cs[4] = {};
    for (int n0 = 0; n0 < 1024; n0 += 64) {
        long go = (long)n0 * 3072;
        u16x8 kr0 = *(const u16x8*)(kfg + go);
        u16x8 kr1 = *(const u16x8*)(kfg + go + 32L * 3072);
        u16x8 ke0, ke1;
        #pragma unroll
        for (int j = 0; j < 8; ++j) {
            ke0[j] = f2b(__expf(b2f(kr0[j])));
            ke1[j] = f2b(__expf(b2f(kr1[j])));
        }
        *(u16x8*)&kf_s[lr * 64 + lc]        = ke0;
        *(u16x8*)&kf_s[(lr + 32) * 64 + lc] = ke1;
        *(u16x8*)&v_s[lr * 64 + lc]         = *(const u16x8*)(vg + go);
        *(u16x8*)&v_s[(lr + 32) * 64 + lc]  = *(const u16x8*)(vg + go + 32L * 3072);
        __syncthreads();
        #pragma unroll 8
        for (int r = 0; r < 64; ++r) {
            u16x4 ku = *(const u16x4*)&kf_s[r * 64 + f0];
            u16x4 vu = *(const u16x4*)&v_s[r * 64 + d0];
            float kf4[4], vf4[4];
            #pragma unroll
            for (int i = 0; i < 4; ++i) { kf4[i] = b2f(ku[i]); vf4[i] = b2f(vu[i]); }
            #pragma unroll
            for (int i = 0; i < 4; ++i) {
                cs[i] += kf4[i];
                #pragma unroll
                for (int jj = 0; jj < 4; ++jj)
                    acc[i][jj] += kf4[i] * vf4[jj];
            }
        }
        __syncthreads();
    }
    float* o = kvp + (long)nc * 524288 + ((long)(b * 16 + h)) * 4096;
    #pragma unroll
    for (int i = 0; i < 4; ++i) {
        #pragma unroll
        for (int jj = 0; jj < 4; ++jj)
            o[(f0 + i) * 64 + d0 + jj] = acc[i][jj];
    }
    if ((t & 15) == 0) {
        float* ps = psum + ((long)nc * 128 + b * 16 + h) * 64 + f0;
        #pragma unroll
        for (int i = 0; i < 4; ++i) ps[i] = cs[i];
    }
}

// --------- combine partials, scale by 1/colsum, transpose -> kvTb[b,h][d][f] bf16 ---
__global__ void kv_combine_T(const float* __restrict__ kvp, const float* __restrict__ psum,
                             u16* __restrict__ kvTb) {
    __shared__ float tl[64 * 65];
    __shared__ float inv_s[64];
    const int bh = blockIdx.x;                       // 128
    const int t = threadIdx.x;
    if (t < 64) {
        float s = psum[((long)0 * 128 + bh) * 64 + t] + psum[((long)1 * 128 + bh) * 64 + t]
                + psum[((long)2 * 128 + bh) * 64 + t] + psum[((long)3 * 128 + bh) * 64 + t];
        inv_s[t] = 1.0f / s;
    }
    __syncthreads();
    const float* p = kvp + (long)bh * 4096;
    #pragma unroll
    for (int it = 0; it < 16; ++it) {
        int idx = it * 256 + t;                      // idx = f*64 + d
        float v = p[idx] + p[524288 + idx] + p[1048576 + idx] + p[1572864 + idx];
        tl[(idx & 63) * 65 + (idx >> 6)] = v * inv_s[idx >> 6];   // tl[d][f]
    }
    __syncthreads();
    u16* o = kvTb + (long)bh * 4096;
    #pragma unroll
    for (int it = 0; it < 16; ++it) {
        int idx = it * 256 + t;                      // idx = d*64 + f
        o[idx] = f2b(tl[(idx >> 6) * 65 + (idx & 63)]);
    }
}

// --------- apply: fused q-softmax + y = q_sm @ kvT per (b,h); y in-place over Q ------
__global__ __launch_bounds__(256) void apply_mfma(u16* __restrict__ qkv,
                                                  const u16* __restrict__ kvTb) {
    __shared__ __align__(16) u16 Qs[8192];   // [128][64] bf16, XOR-swizzled chunks
    const int t = threadIdx.x;
    const int bx = blockIdx.x;               // 4096 = 32nt * 16h * 8b
    const int nt = bx & 31, h = (bx >> 5) & 15, b = bx >> 9;
    const long n0 = (long)b * 4096 + (long)nt * 128;
    const int wave = t >> 6, lane = t & 63;
    const int wr = wave >> 1, wc = wave & 1;
    const int l16 = lane & 15, g = lane >> 4;

    // ---- fused q-softmax: 4 passes x 32 rows; 8 lanes per row x 8 elems ----
    const int colg = t & 7;
    const int rloc = t >> 3;                 // 0..31
    #pragma unroll
    for (int p = 0; p < 4; ++p) {
        const int row = p * 32 + rloc;       // 0..127
        u16x8 qv = *(const u16x8*)(qkv + (n0 + row) * 3072 + h * 64 + colg * 8);
        float f[8];
        #pragma unroll
        for (int j = 0; j < 8; ++j) f[j] = b2f(qv[j]);
        float m = f[0];
        #pragma unroll
        for (int j = 1; j < 8; ++j) m = fmaxf(m, f[j]);
        m = fmaxf(m, __shfl_xor(m, 1)); m = fmaxf(m, __shfl_xor(m, 2)); m = fmaxf(m, __shfl_xor(m, 4));
        float s = 0.f;
        #pragma unroll
        for (int j = 0; j < 8; ++j) { f[j] = __expf(f[j] - m); s += f[j]; }
        s += __shfl_xor(s, 1); s += __shfl_xor(s, 2); s += __shfl_xor(s, 4);
        const float sc = 0.125f / s;         // includes D^-0.5
        u16x8 ov;
        #pragma unroll
        for (int j = 0; j < 8; ++j) ov[j] = f2b(f[j] * sc);
        const int chunk = colg ^ (row & 7);
        *(u16x8*)&Qs[row * 64 + chunk * 8] = ov;
    }
    __syncthreads();

    // ---- B frags direct from global (kvTb tiny, L2-resident) ----
    const u16* kvb = kvTb + ((long)(b * 16 + h) << 12);
    bf16x8v bkv[2][2];
    #pragma unroll
    for (int ni = 0; ni < 2; ++ni) {
        #pragma unroll
        for (int ks = 0; ks < 2; ++ks)
            bkv[ni][ks] = __builtin_bit_cast(bf16x8v,
                *(const u16x8*)(kvb + (wc * 32 + ni * 16 + l16) * 64 + ks * 32 + g * 8));
    }
    // ---- A frags from swizzled LDS ----
    bf16x8v aq[4][2];
    #pragma unroll
    for (int mi = 0; mi < 4; ++mi) {
        const int row = wr * 64 + mi * 16 + l16;
        #pragma unroll
        for (int ks = 0; ks < 2; ++ks) {
            const int c16 = (ks * 4 + g) ^ (row & 7);
            aq[mi][ks] = __builtin_bit_cast(bf16x8v,
                *(const u16x8*)&Qs[row * 64 + c16 * 8]);
        }
    }
    f32x4 acc[4][2] = {};
    #pragma unroll
    for (int mi = 0; mi < 4; ++mi) {
        #pragma unroll
        for (int ni = 0; ni < 2; ++ni) {
            acc[mi][ni] = __builtin_amdgcn_mfma_f32_16x16x32_bf16(
                aq[mi][0], bkv[ni][0], acc[mi][ni], 0, 0, 0);
            acc[mi][ni] = __builtin_amdgcn_mfma_f32_16x16x32_bf16(
                aq[mi][1], bkv[ni][1], acc[mi][ni], 0, 0, 0);
        }
    }
    #pragma unroll
    for (int mi = 0; mi < 4; ++mi) {
        #pragma unroll
        for (int ni = 0; ni < 2; ++ni) {
            long row = n0 + wr * 64 + mi * 16 + g * 4;
            int col = h * 64 + wc * 32 + ni * 16 + l16;
            #pragma unroll
            for (int r = 0; r < 4; ++r)
                qkv[(row + r) * 3072 + col] = f2b(acc[mi][ni][r]);
        }
    }
}

extern "C" void kernel_launch(void* const* d_in, const int* in_sizes, int n_in,
                              void* d_out, int out_size, void* d_ws, size_t ws_size,
                              hipStream_t stream) {
    (void)in_sizes; (void)n_in; (void)out_size; (void)ws_size;
    const float* x  = (const float*)d_in[0];
    const float* Wq = (const float*)d_in[1];
    const float* Wk = (const float*)d_in[2];
    const float* Wv = (const float*)d_in[3];
    const float* Wo = (const float*)d_in[4];
    const float* bo = (const float*)d_in[5];

    u16* xb  = (u16*)d_ws;                       // 33,554,432 elems
    u16* wt  = xb + 33554432;                    //  3,145,728
    u16* wot = wt + 3145728;                     //  1,048,576
    u16* qkv = wot + 1048576;                    // 100,663,296
    float* psum = (float*)(qkv + 100663296);     //     32,768
    float* kvp  = psum + 32768;                  //  2,097,152
    u16*   kvTb = (u16*)(kvp + 2097152);         //    524,288

    cast_x_kernel<<<2048, 256, 0, stream>>>(x, xb, 8388608L);
    transpose_cast<<<256, 256, 0, stream>>>(Wq, wt);
    transpose_cast<<<256, 256, 0, stream>>>(Wk, wt + 1048576);
    transpose_cast<<<256, 256, 0, stream>>>(Wv, wt + 2097152);
    transpose_cast<<<256, 256, 0, stream>>>(Wo, wot);
    // QKV = xb @ [Wq|Wk|Wv]^T-laid   (M=32768, N=3072, K=1024)
    gemm256<0><<<1536, 512, 0, stream>>>(xb, wt, (void*)qkv, nullptr, 1024, 3072, 12, 1536);
    kv_partial<<<512, 256, 0, stream>>>(qkv, kvp, psum);
    kv_combine_T<<<128, 256, 0, stream>>>(kvp, psum, kvTb);
    apply_mfma<<<4096, 256, 0, stream>>>(qkv, kvTb);
    // out = y @ Wo + bo   (M=32768, N=1024, K=1024), y in Q region (lda=3072)
    gemm256<1><<<512, 512, 0, stream>>>(qkv, wot, d_out, bo, 3072, 1024, 4, 512);
}

// Round 3
// 445.020 us; speedup vs baseline: 1.5472x; 1.0699x over previous
//
#include <hip/hip_runtime.h>

// VanillaLinearAttention: B=8 N=4096 C=1024 H=16 D=64, M=B*N=32768.
// cast x -> bf16; transpose W's; QKV = x@[Wq|Wk|Wv] (256^2 counted-vmcnt MFMA
// GEMM, 2-way-free LDS swizzle); kv = sum_n exp(k)*v (f32 LDS, colsum fused);
// kv_combine applies 1/colsum + transpose; apply = fused q-softmax + q@kvT
// MFMA (y in-place over Q); out = y@Wo + bo.

typedef unsigned short u16;
typedef __bf16 bf16x8v __attribute__((ext_vector_type(8)));
typedef float f32x4 __attribute__((ext_vector_type(4)));
typedef u16 u16x8 __attribute__((ext_vector_type(8)));
typedef u16 u16x4 __attribute__((ext_vector_type(4)));

#define AS1C(p) (const __attribute__((address_space(1))) void*)(p)
#define AS3(p)  (__attribute__((address_space(3))) void*)(p)

__device__ __forceinline__ float b2f(u16 u) {
    union { unsigned u; float f; } c; c.u = ((unsigned)u) << 16; return c.f;
}
__device__ __forceinline__ u16 f2b(float f) {
    union { float f; unsigned u; } c; c.f = f;
    unsigned x = c.u + 0x7fffu + ((c.u >> 16) & 1u);   // RNE
    return (u16)(x >> 16);
}

// ---------------- cast x fp32 -> bf16 ----------------
__global__ void cast_x_kernel(const float* __restrict__ in, u16* __restrict__ out, long n4) {
    long i = (long)blockIdx.x * blockDim.x + threadIdx.x;
    long stride = (long)gridDim.x * blockDim.x;
    for (long j = i; j < n4; j += stride) {
        float4 v = ((const float4*)in)[j];
        u16x4 o = { f2b(v.x), f2b(v.y), f2b(v.z), f2b(v.w) };
        ((u16x4*)out)[j] = o;
    }
}

// ------------- transpose+cast 1024x1024: dst[n][k] = src[k][n] -------------
__global__ void transpose_cast(const float* __restrict__ src, u16* __restrict__ dst) {
    __shared__ float tl[64][65];
    int tx = blockIdx.x & 15, ty = blockIdx.x >> 4;
    int j = threadIdx.x & 63, i0 = threadIdx.x >> 6;
    #pragma unroll
    for (int it = 0; it < 16; ++it) {
        int i = it * 4 + i0;
        tl[i][j] = src[(ty * 64 + i) * 1024 + tx * 64 + j];
    }
    __syncthreads();
    #pragma unroll
    for (int it = 0; it < 16; ++it) {
        int i = it * 4 + i0;
        dst[(tx * 64 + i) * 1024 + ty * 64 + j] = f2b(tl[j][i]);
    }
}

// ================= 256x256-tile NT-GEMM, BK=32, counted-vmcnt 4-buf ring ======
// C[M][N] = A[M][K=1024] * Bt[N][1024]^T.  512 thr = 8 waves (2M x 4N),
// per-wave 128x64 = 8x4 16x16x32 frags. LDS: 4 bufs x (A 16K + B 16K) = 128 KB.
// Swizzle: 16B chunk slot = k-group ^ ((row>>1)&3)  (bank-period-2 aware;
// 16-lane column reads hit 8 distinct banks -> 2-way = free).
template<int OUTMODE>
__global__ __launch_bounds__(512, 2) void gemm256(
    const u16* __restrict__ A, const u16* __restrict__ Bt,
    void* __restrict__ Cout, const float* __restrict__ bias,
    const int lda, const int ldc, const int ntn, const int nwg)
{
    __shared__ __align__(16) u16 lds[65536];   // 128 KB
    const int t = threadIdx.x;
    const int w = t >> 6, lane = t & 63;
    const int l16 = lane & 15, g = lane >> 4;
    const int wr = w >> 2, wc = w & 3;

    // XCD-aware bijective swizzle (nwg % 8 == 0)
    const int cpx = nwg >> 3;
    const int bid = blockIdx.x;
    const int swzb = (bid & 7) * cpx + (bid >> 3);
    const int tm = swzb / ntn, tn = swzb - tm * ntn;
    const long row0 = (long)tm << 8, col0 = (long)tn << 8;

    // staging: thread t covers row r0=t>>2, 16B slot s=t&3; slot s holds
    // k-group s ^ ((r0>>1)&3)  ->  global elem offset below
    const int r0 = t >> 2;
    const int eo = (((t & 3) ^ ((t >> 3) & 3)) << 3);
    const u16* pa0 = A + (row0 + r0) * (long)lda + eo;
    const u16* pa1 = A + (row0 + 128 + r0) * (long)lda + eo;
    const u16* pb0 = Bt + (col0 + r0) * 1024L + eo;
    const u16* pb1 = Bt + (col0 + 128 + r0) * 1024L + eo;
    const int wB = w << 9;                                 // wave LDS base (elems)

#define STAGE_A(Tt) { const int _b = ((Tt)&3)*16384; const int _k = ((Tt)&31)*32;        \
    __builtin_amdgcn_global_load_lds(AS1C(pa0 + _k), AS3(lds + _b + wB), 16, 0, 0);      \
    __builtin_amdgcn_global_load_lds(AS1C(pa1 + _k), AS3(lds + _b + 4096 + wB), 16, 0, 0); }
#define STAGE_B(Tt) { const int _b = ((Tt)&3)*16384; const int _k = ((Tt)&31)*32;        \
    __builtin_amdgcn_global_load_lds(AS1C(pb0 + _k), AS3(lds + _b + 8192 + wB), 16, 0, 0);  \
    __builtin_amdgcn_global_load_lds(AS1C(pb1 + _k), AS3(lds + _b + 12288 + wB), 16, 0, 0); }

    // prologue: prefetch tiles 0,1,2
    STAGE_A(0); STAGE_B(0);
    STAGE_A(1); STAGE_B(1);
    STAGE_A(2); STAGE_B(2);

    f32x4 acc[8][4] = {};
    const int sw = ((g ^ ((l16 >> 1) & 3)) << 3);   // read-side swizzle (elems)
    const int arow = wr * 128 + l16;                // A frag base row
    const int brow = wc * 64 + l16;                 // B frag base row

    #pragma unroll 4
    for (int T = 0; T < 32; ++T) {
        const int bufE = (T & 3) * 16384;
        const int Tn = T + 3;
        // ---- phase 0: issue A-stage(T+3); wait tile T; quadrant mi 0..3 ----
        STAGE_A(Tn);
        asm volatile("s_waitcnt vmcnt(10)" ::: "memory");
        __builtin_amdgcn_s_barrier();
        __builtin_amdgcn_sched_barrier(0);
        bf16x8v bfr[4], afr[4];
        #pragma unroll
        for (int ni = 0; ni < 4; ++ni)
            bfr[ni] = __builtin_bit_cast(bf16x8v,
                *(const u16x8*)&lds[bufE + 8192 + (brow + ni * 16) * 32 + sw]);
        #pragma unroll
        for (int mi = 0; mi < 4; ++mi)
            afr[mi] = __builtin_bit_cast(bf16x8v,
                *(const u16x8*)&lds[bufE + (arow + mi * 16) * 32 + sw]);
        __builtin_amdgcn_s_setprio(1);
        #pragma unroll
        for (int mi = 0; mi < 4; ++mi) {
            #pragma unroll
            for (int ni = 0; ni < 4; ++ni)
                acc[mi][ni] = __builtin_amdgcn_mfma_f32_16x16x32_bf16(
                    afr[mi], bfr[ni], acc[mi][ni], 0, 0, 0);
        }
        __builtin_amdgcn_s_setprio(0);
        // ---- phase 1: issue B-stage(T+3); quadrant mi 4..7 ----
        STAGE_B(Tn);
        bf16x8v afr2[4];
        #pragma unroll
        for (int mi = 0; mi < 4; ++mi)
            afr2[mi] = __builtin_bit_cast(bf16x8v,
                *(const u16x8*)&lds[bufE + (arow + 64 + mi * 16) * 32 + sw]);
        __builtin_amdgcn_s_setprio(1);
        #pragma unroll
        for (int mi = 0; mi < 4; ++mi) {
            #pragma unroll
            for (int ni = 0; ni < 4; ++ni)
                acc[4 + mi][ni] = __builtin_amdgcn_mfma_f32_16x16x32_bf16(
                    afr2[mi], bfr[ni], acc[4 + mi][ni], 0, 0, 0);
        }
        __builtin_amdgcn_s_setprio(0);
        __builtin_amdgcn_s_barrier();          // all waves done reading buf[T&3]
        __builtin_amdgcn_sched_barrier(0);
    }
    asm volatile("s_waitcnt vmcnt(0)" ::: "memory");   // drain tail stages
#undef STAGE_A
#undef STAGE_B

    // C/D: col = lane&15, row = (lane>>4)*4 + reg
    const long crow = row0 + wr * 128 + g * 4;
    const long ccol = col0 + wc * 64 + l16;
    if (OUTMODE == 0) {
        u16* Cb = (u16*)Cout;
        #pragma unroll
        for (int mi = 0; mi < 8; ++mi) {
            #pragma unroll
            for (int ni = 0; ni < 4; ++ni) {
                long base = (crow + mi * 16) * (long)ldc + ccol + ni * 16;
                #pragma unroll
                for (int r = 0; r < 4; ++r)
                    Cb[base + (long)r * ldc] = f2b(acc[mi][ni][r]);
            }
        }
    } else {
        float* Cf = (float*)Cout;
        float bv[4];
        #pragma unroll
        for (int ni = 0; ni < 4; ++ni) bv[ni] = bias[ccol + ni * 16];
        #pragma unroll
        for (int mi = 0; mi < 8; ++mi) {
            #pragma unroll
            for (int ni = 0; ni < 4; ++ni) {
                long base = (crow + mi * 16) * (long)ldc + ccol + ni * 16;
                #pragma unroll
                for (int r = 0; r < 4; ++r)
                    Cf[base + (long)r * ldc] = acc[mi][ni][r] + bv[ni];
            }
        }
    }
}

// --------- kv[b,h,f,d] = sum_n exp(k_raw)[n,h,f] * v[n,h,d]; colsum side-product ---
// f32 LDS staging (exp fused), pad-68 stride, 8 n-chunks.
__global__ __launch_bounds__(256) void kv_partial(const u16* __restrict__ qkv,
                                                  float* __restrict__ kvp,
                                                  float* __restrict__ psum) {
    __shared__ __align__(16) float kf_s[64 * 68];
    __shared__ __align__(16) float v_s[64 * 68];
    const int t = threadIdx.x;
    const int bx = blockIdx.x;                       // 1024 = 8nc * 16h * 8b
    const int nc = bx & 7, h = (bx >> 3) & 15, b = bx >> 7;
    const int f0 = (t >> 4) << 2;                    // 0..60
    const int d0 = (t & 15) << 2;
    const int lr = t >> 3, lc = (t & 7) << 3;
    const long rowbase = (long)b * 4096 + nc * 512;
    const u16* kfg = qkv + (rowbase + lr) * 3072 + 1024 + h * 64 + lc;
    const u16* vg = kfg + 1024;
    float acc[4][4] = {};
    float cs[4] = {};
    for (int n0 = 0; n0 < 512; n0 += 64) {
        long go = (long)n0 * 3072;
        u16x8 kr0 = *(const u16x8*)(kfg + go);
        u16x8 kr1 = *(const u16x8*)(kfg + go + 32L * 3072);
        u16x8 vr0 = *(const u16x8*)(vg + go);
        u16x8 vr1 = *(const u16x8*)(vg + go + 32L * 3072);
        f32x4 ke0a, ke0b, ke1a, ke1b, vv0a, vv0b, vv1a, vv1b;
        #pragma unroll
        for (int j = 0; j < 4; ++j) {
            ke0a[j] = __expf(b2f(kr0[j]));     ke0b[j] = __expf(b2f(kr0[j + 4]));
            ke1a[j] = __expf(b2f(kr1[j]));     ke1b[j] = __expf(b2f(kr1[j + 4]));
            vv0a[j] = b2f(vr0[j]);             vv0b[j] = b2f(vr0[j + 4]);
            vv1a[j] = b2f(vr1[j]);             vv1b[j] = b2f(vr1[j + 4]);
        }
        *(f32x4*)&kf_s[lr * 68 + lc]            = ke0a;
        *(f32x4*)&kf_s[lr * 68 + lc + 4]        = ke0b;
        *(f32x4*)&kf_s[(lr + 32) * 68 + lc]     = ke1a;
        *(f32x4*)&kf_s[(lr + 32) * 68 + lc + 4] = ke1b;
        *(f32x4*)&v_s[lr * 68 + lc]             = vv0a;
        *(f32x4*)&v_s[lr * 68 + lc + 4]         = vv0b;
        *(f32x4*)&v_s[(lr + 32) * 68 + lc]      = vv1a;
        *(f32x4*)&v_s[(lr + 32) * 68 + lc + 4]  = vv1b;
        __syncthreads();
        #pragma unroll 8
        for (int r = 0; r < 64; ++r) {
            f32x4 kf4 = *(const f32x4*)&kf_s[r * 68 + f0];
            f32x4 vf4 = *(const f32x4*)&v_s[r * 68 + d0];
            #pragma unroll
            for (int i = 0; i < 4; ++i) {
                cs[i] += kf4[i];
                #pragma unroll
                for (int jj = 0; jj < 4; ++jj)
                    acc[i][jj] += kf4[i] * vf4[jj];
            }
        }
        __syncthreads();
    }
    float* o = kvp + (long)nc * 524288 + ((long)(b * 16 + h)) * 4096;
    #pragma unroll
    for (int i = 0; i < 4; ++i) {
        #pragma unroll
        for (int jj = 0; jj < 4; ++jj)
            o[(f0 + i) * 64 + d0 + jj] = acc[i][jj];
    }
    if ((t & 15) == 0) {
        float* ps = psum + ((long)nc * 128 + b * 16 + h) * 64 + f0;
        #pragma unroll
        for (int i = 0; i < 4; ++i) ps[i] = cs[i];
    }
}

// --------- combine 8 partials, scale by 1/colsum, transpose -> kvTb[b,h][d][f] bf16 ---
__global__ void kv_combine_T(const float* __restrict__ kvp, const float* __restrict__ psum,
                             u16* __restrict__ kvTb) {
    __shared__ float tl[64 * 65];
    __shared__ float inv_s[64];
    const int bh = blockIdx.x;                       // 128
    const int t = threadIdx.x;
    if (t < 64) {
        float s = 0.f;
        #pragma unroll
        for (int nc = 0; nc < 8; ++nc) s += psum[((long)nc * 128 + bh) * 64 + t];
        inv_s[t] = 1.0f / s;
    }
    __syncthreads();
    const float* p = kvp + (long)bh * 4096;
    #pragma unroll
    for (int it = 0; it < 16; ++it) {
        int idx = it * 256 + t;                      // idx = f*64 + d
        float v = 0.f;
        #pragma unroll
        for (int nc = 0; nc < 8; ++nc) v += p[(long)nc * 524288 + idx];
        tl[(idx & 63) * 65 + (idx >> 6)] = v * inv_s[idx >> 6];   // tl[d][f]
    }
    __syncthreads();
    u16* o = kvTb + (long)bh * 4096;
    #pragma unroll
    for (int it = 0; it < 16; ++it) {
        int idx = it * 256 + t;                      // idx = d*64 + f
        o[idx] = f2b(tl[(idx >> 6) * 65 + (idx & 63)]);
    }
}

// --------- apply: fused q-softmax + y = q_sm @ kvT per (b,h); y in-place over Q ------
__global__ __launch_bounds__(256) void apply_mfma(u16* __restrict__ qkv,
                                                  const u16* __restrict__ kvTb) {
    __shared__ __align__(16) u16 Qs[8192];   // [128][64] bf16, XOR-swizzled chunks
    const int t = threadIdx.x;
    const int bx = blockIdx.x;               // 4096 = 32nt * 16h * 8b
    const int nt = bx & 31, h = (bx >> 5) & 15, b = bx >> 9;
    const long n0 = (long)b * 4096 + (long)nt * 128;
    const int wave = t >> 6, lane = t & 63;
    const int wr = wave >> 1, wc = wave & 1;
    const int l16 = lane & 15, g = lane >> 4;

    // ---- fused q-softmax: 4 passes x 32 rows; 8 lanes per row x 8 elems ----
    const int colg = t & 7;
    const int rloc = t >> 3;                 // 0..31
    #pragma unroll
    for (int p = 0; p < 4; ++p) {
        const int row = p * 32 + rloc;       // 0..127
        u16x8 qv = *(const u16x8*)(qkv + (n0 + row) * 3072 + h * 64 + colg * 8);
        float f[8];
        #pragma unroll
        for (int j = 0; j < 8; ++j) f[j] = b2f(qv[j]);
        float m = f[0];
        #pragma unroll
        for (int j = 1; j < 8; ++j) m = fmaxf(m, f[j]);
        m = fmaxf(m, __shfl_xor(m, 1)); m = fmaxf(m, __shfl_xor(m, 2)); m = fmaxf(m, __shfl_xor(m, 4));
        float s = 0.f;
        #pragma unroll
        for (int j = 0; j < 8; ++j) { f[j] = __expf(f[j] - m); s += f[j]; }
        s += __shfl_xor(s, 1); s += __shfl_xor(s, 2); s += __shfl_xor(s, 4);
        const float sc = 0.125f / s;         // includes D^-0.5
        u16x8 ov;
        #pragma unroll
        for (int j = 0; j < 8; ++j) ov[j] = f2b(f[j] * sc);
        const int chunk = colg ^ (row & 7);
        *(u16x8*)&Qs[row * 64 + chunk * 8] = ov;
    }
    __syncthreads();

    // ---- B frags direct from global (kvTb tiny, L2-resident) ----
    const u16* kvb = kvTb + ((long)(b * 16 + h) << 12);
    bf16x8v bkv[2][2];
    #pragma unroll
    for (int ni = 0; ni < 2; ++ni) {
        #pragma unroll
        for (int ks = 0; ks < 2; ++ks)
            bkv[ni][ks] = __builtin_bit_cast(bf16x8v,
                *(const u16x8*)(kvb + (wc * 32 + ni * 16 + l16) * 64 + ks * 32 + g * 8));
    }
    // ---- A frags from swizzled LDS ----
    bf16x8v aq[4][2];
    #pragma unroll
    for (int mi = 0; mi < 4; ++mi) {
        const int row = wr * 64 + mi * 16 + l16;
        #pragma unroll
        for (int ks = 0; ks < 2; ++ks) {
            const int c16 = (ks * 4 + g) ^ (row & 7);
            aq[mi][ks] = __builtin_bit_cast(bf16x8v,
                *(const u16x8*)&Qs[row * 64 + c16 * 8]);
        }
    }
    f32x4 acc[4][2] = {};
    #pragma unroll
    for (int mi = 0; mi < 4; ++mi) {
        #pragma unroll
        for (int ni = 0; ni < 2; ++ni) {
            acc[mi][ni] = __builtin_amdgcn_mfma_f32_16x16x32_bf16(
                aq[mi][0], bkv[ni][0], acc[mi][ni], 0, 0, 0);
            acc[mi][ni] = __builtin_amdgcn_mfma_f32_16x16x32_bf16(
                aq[mi][1], bkv[ni][1], acc[mi][ni], 0, 0, 0);
        }
    }
    #pragma unroll
    for (int mi = 0; mi < 4; ++mi) {
        #pragma unroll
        for (int ni = 0; ni < 2; ++ni) {
            long row = n0 + wr * 64 + mi * 16 + g * 4;
            int col = h * 64 + wc * 32 + ni * 16 + l16;
            #pragma unroll
            for (int r = 0; r < 4; ++r)
                qkv[(row + r) * 3072 + col] = f2b(acc[mi][ni][r]);
        }
    }
}

extern "C" void kernel_launch(void* const* d_in, const int* in_sizes, int n_in,
                              void* d_out, int out_size, void* d_ws, size_t ws_size,
                              hipStream_t stream) {
    (void)in_sizes; (void)n_in; (void)out_size; (void)ws_size;
    const float* x  = (const float*)d_in[0];
    const float* Wq = (const float*)d_in[1];
    const float* Wk = (const float*)d_in[2];
    const float* Wv = (const float*)d_in[3];
    const float* Wo = (const float*)d_in[4];
    const float* bo = (const float*)d_in[5];

    u16* xb  = (u16*)d_ws;                       // 33,554,432 elems (64 MB)
    u16* wt  = xb + 33554432;                    //  3,145,728
    u16* wot = wt + 3145728;                     //  1,048,576
    u16* qkv = wot + 1048576;                    // 100,663,296
    u16*   kvTb = qkv + 100663296;               //    524,288
    // kvp/psum alias the xb region (xb dead after gemm<0>; rewritten by cast_x
    // at the start of every call). kvp: 8*524288 f32 = 16.8 MB; psum 64 KB.
    float* kvp  = (float*)xb;                    //  4,194,304 f32
    float* psum = kvp + 4194304;                 //     65,536 f32

    cast_x_kernel<<<2048, 256, 0, stream>>>(x, xb, 8388608L);
    transpose_cast<<<256, 256, 0, stream>>>(Wq, wt);
    transpose_cast<<<256, 256, 0, stream>>>(Wk, wt + 1048576);
    transpose_cast<<<256, 256, 0, stream>>>(Wv, wt + 2097152);
    transpose_cast<<<256, 256, 0, stream>>>(Wo, wot);
    // QKV = xb @ [Wq|Wk|Wv]^T-laid   (M=32768, N=3072, K=1024)
    gemm256<0><<<1536, 512, 0, stream>>>(xb, wt, (void*)qkv, nullptr, 1024, 3072, 12, 1536);
    kv_partial<<<1024, 256, 0, stream>>>(qkv, kvp, psum);
    kv_combine_T<<<128, 256, 0, stream>>>(kvp, psum, kvTb);
    apply_mfma<<<4096, 256, 0, stream>>>(qkv, kvTb);
    // out = y @ Wo + bo   (M=32768, N=1024, K=1024), y in Q region (lda=3072)
    gemm256<1><<<512, 512, 0, stream>>>(qkv, wot, d_out, bo, 3072, 1024, 4, 512);
}